// Round 4
// baseline (2007.680 us; speedup 1.0000x reference)
//
#include <hip/hip_runtime.h>
#include <hip/hip_bf16.h>

#define NT 4096
#define INDIM 1024
#define HID 512
#define NHEADS 4
#define DH 128
#define TBL 9332
#define WGRID 300
#define CUNIT 896.0f
#define QSCALE 0.08838834764831843f  // 1/sqrt(128)

typedef unsigned short u16;
typedef __bf16 bf16x8 __attribute__((ext_vector_type(8)));
typedef float f32x4 __attribute__((ext_vector_type(4)));
typedef short short8 __attribute__((ext_vector_type(8)));

__device__ __forceinline__ u16 f2bf(float f) {
  unsigned u = __float_as_uint(f);
  unsigned r = (u + 0x7FFFu + ((u >> 16) & 1u)) >> 16;
  return (u16)r;
}

__device__ __forceinline__ unsigned fenc(float f) {
  unsigned b = __float_as_uint(f);
  return (b & 0x80000000u) ? ~b : (b ^ 0x80000000u);
}
__device__ __forceinline__ float fdec(unsigned u) {
  unsigned b = (u & 0x80000000u) ? (u ^ 0x80000000u) : ~u;
  return __uint_as_float(b);
}

// ---------------- casts ----------------
__global__ void cast_x_kernel(const float* __restrict__ x, u16* __restrict__ xin) {
  int total = NT * INDIM;
  for (int i = blockIdx.x * blockDim.x + threadIdx.x; i < total; i += gridDim.x * blockDim.x) {
    int r = i >> 10, c = i & 1023;
    xin[i] = f2bf(x[r * 1026 + c]);
  }
}

// W (K x Nn) f32 -> Wt (Nn x K) bf16
__global__ void cast_tr_kernel(const float* __restrict__ w, u16* __restrict__ wt, int K, int Nn) {
  int total = K * Nn;
  for (int i = blockIdx.x * blockDim.x + threadIdx.x; i < total; i += gridDim.x * blockDim.x) {
    int k = i / Nn, n = i % Nn;
    wt[(size_t)n * K + k] = f2bf(w[i]);
  }
}

// ---------------- init / idx / bias ----------------
__global__ void init_kernel(float* colsum, unsigned* bminenc) {
  int t = threadIdx.x;
  colsum[t] = 0.f;
  colsum[t + 256] = 0.f;
  if (t == 0) *bminenc = 0xFFFFFFFFu;
}

__global__ void coordmin_kernel(const float* __restrict__ x, float* __restrict__ cmin) {
  int t = threadIdx.x;
  float mx = 1e30f, my = 1e30f;
  for (int i = t; i < NT; i += 256) {
    mx = fminf(mx, x[(size_t)i * 1026 + 1024]);
    my = fminf(my, x[(size_t)i * 1026 + 1025]);
  }
  for (int d = 1; d < 64; d <<= 1) {
    mx = fminf(mx, __shfl_xor(mx, d, 64));
    my = fminf(my, __shfl_xor(my, d, 64));
  }
  __shared__ float sx[4], sy[4];
  int w = t >> 6;
  if ((t & 63) == 0) { sx[w] = mx; sy[w] = my; }
  __syncthreads();
  if (t == 0) {
    cmin[0] = fminf(fminf(sx[0], sx[1]), fminf(sx[2], sx[3]));
    cmin[1] = fminf(fminf(sy[0], sy[1]), fminf(sy[2], sy[3]));
  }
}

__global__ void idx_kernel(const float* __restrict__ x, const float* __restrict__ cmin,
                           int* __restrict__ idx) {
  int i = blockIdx.x * 256 + threadIdx.x;
  if (i < NT) {
    float xp = rintf((x[(size_t)i * 1026 + 1024] - cmin[0]) / CUNIT);
    float yp = rintf((x[(size_t)i * 1026 + 1025] - cmin[1]) / CUNIT);
    idx[i] = (int)(xp * (float)WGRID + yp);
  }
}

__global__ void bias_gather_kernel(const float* __restrict__ tbl, const int* __restrict__ idx,
                                   float* __restrict__ B, unsigned* __restrict__ bminenc) {
  int n = blockIdx.x;
  size_t rowoff = (size_t)idx[n] * TBL;
  float lmin = 1e30f;
  float* Brow = B + (size_t)n * NT;
  for (int m = threadIdx.x; m < NT; m += 256) {
    float v = tbl[rowoff + idx[m]];
    Brow[m] = v;
    lmin = fminf(lmin, v);
  }
  for (int d = 1; d < 64; d <<= 1) lmin = fminf(lmin, __shfl_xor(lmin, d, 64));
  __shared__ float sm[4];
  int w = threadIdx.x >> 6;
  if ((threadIdx.x & 63) == 0) sm[w] = lmin;
  __syncthreads();
  if (threadIdx.x == 0) {
    float bm = fminf(fminf(sm[0], sm[1]), fminf(sm[2], sm[3]));
    atomicMin(bminenc, fenc(bm));
  }
}

// ---------------- GEMM ----------------
#define EPI_RELU 0
#define EPI_QKV  1
#define EPI_ADD  2
#define EPI_GELU 3

template <int EPI>
__global__ __launch_bounds__(256) void gemm_kernel(
    const u16* __restrict__ A, const u16* __restrict__ Wt, const float* __restrict__ bias,
    float* __restrict__ outf, u16* __restrict__ outb,
    u16* __restrict__ qb_, u16* __restrict__ kb_, u16* __restrict__ vtb_,
    int Nn, int K) {
  __shared__ u16 As[128][72];
  __shared__ u16 Bs[64][72];
  int tid = threadIdx.x;
  int w = tid >> 6, l = tid & 63;
  int g = l >> 4, c16 = l & 15;
  int brow = blockIdx.y * 128, bcol = blockIdx.x * 64;
  int wr = (w >> 1) * 64, wc = (w & 1) * 32;
  f32x4 acc[4][2];
  for (int a = 0; a < 4; ++a)
    for (int b = 0; b < 2; ++b) acc[a][b] = (f32x4){0.f, 0.f, 0.f, 0.f};
  int trow = tid >> 3, tcol = (tid & 7) * 8;
  for (int k0 = 0; k0 < K; k0 += 64) {
    for (int p = 0; p < 4; ++p) {
      int r = p * 32 + trow;
      *(short8*)&As[r][tcol] = *(const short8*)&A[(size_t)(brow + r) * K + k0 + tcol];
    }
    for (int p = 0; p < 2; ++p) {
      int r = p * 32 + trow;
      *(short8*)&Bs[r][tcol] = *(const short8*)&Wt[(size_t)(bcol + r) * K + k0 + tcol];
    }
    __syncthreads();
    for (int kk = 0; kk < 2; ++kk) {
      bf16x8 af[4], bfr[2];
      for (int rf = 0; rf < 4; ++rf)
        af[rf] = *(const bf16x8*)&As[wr + rf * 16 + c16][kk * 32 + g * 8];
      for (int cf = 0; cf < 2; ++cf)
        bfr[cf] = *(const bf16x8*)&Bs[wc + cf * 16 + c16][kk * 32 + g * 8];
      for (int rf = 0; rf < 4; ++rf)
        for (int cf = 0; cf < 2; ++cf)
          acc[rf][cf] = __builtin_amdgcn_mfma_f32_16x16x32_bf16(af[rf], bfr[cf], acc[rf][cf], 0, 0, 0);
    }
    __syncthreads();
  }
  for (int rf = 0; rf < 4; ++rf)
    for (int cf = 0; cf < 2; ++cf)
      for (int j = 0; j < 4; ++j) {
        int row = brow + wr + rf * 16 + 4 * g + j;
        int col = bcol + wc + cf * 16 + c16;
        float val = acc[rf][cf][j];
        if constexpr (EPI == EPI_RELU) {
          val += bias[col];
          outf[(size_t)row * Nn + col] = fmaxf(val, 0.f);
        } else if constexpr (EPI == EPI_ADD) {
          val += bias[col];
          outf[(size_t)row * Nn + col] += val;
        } else if constexpr (EPI == EPI_GELU) {
          val += bias[col];
          val = 0.5f * val * (1.f + erff(val * 0.70710678118f));
          outb[(size_t)row * Nn + col] = f2bf(val);
        } else {  // QKV (no bias)
          int which = col >> 9, rem = col & 511, hh = rem >> 7, d = rem & 127;
          if (which == 0)
            qb_[((size_t)(hh * NT + row)) * DH + d] = f2bf(val * QSCALE);
          else if (which == 1)
            kb_[((size_t)(hh * NT + row)) * DH + d] = f2bf(val);
          else
            vtb_[((size_t)(hh * DH + d)) * NT + row] = f2bf(val);
        }
      }
}

// ---------------- LayerNorm (rows of h f32 -> bf16) ----------------
__global__ __launch_bounds__(256) void ln_kernel(const float* __restrict__ hsrc,
                                                 const float* __restrict__ s,
                                                 const float* __restrict__ b,
                                                 u16* __restrict__ out) {
  int w = threadIdx.x >> 6, l = threadIdx.x & 63;
  int row = blockIdx.x * 4 + w;
  const float* hr = hsrc + (size_t)row * HID;
  int c0 = l * 8;
  float v[8];
  f32x4 va = *(const f32x4*)&hr[c0];
  f32x4 vb = *(const f32x4*)&hr[c0 + 4];
  v[0] = va[0]; v[1] = va[1]; v[2] = va[2]; v[3] = va[3];
  v[4] = vb[0]; v[5] = vb[1]; v[6] = vb[2]; v[7] = vb[3];
  float sum = 0.f;
  for (int i = 0; i < 8; ++i) sum += v[i];
  for (int d = 1; d < 64; d <<= 1) sum += __shfl_xor(sum, d, 64);
  float mean = sum * (1.f / HID);
  float s2 = 0.f;
  for (int i = 0; i < 8; ++i) { float dd = v[i] - mean; s2 += dd * dd; }
  for (int d = 1; d < 64; d <<= 1) s2 += __shfl_xor(s2, d, 64);
  float rstd = rsqrtf(s2 * (1.f / HID) + 1e-5f);
  u16 o[8] __attribute__((aligned(16)));
  for (int i = 0; i < 8; ++i)
    o[i] = f2bf((v[i] - mean) * rstd * s[c0 + i] + b[c0 + i]);
  *(short8*)&out[(size_t)row * HID + c0] = *(const short8*)o;
}

// ---------------- Flash attention with gathered bias ----------------
__global__ __launch_bounds__(256) void attn_kernel(
    const u16* __restrict__ q, const u16* __restrict__ k, const u16* __restrict__ vt,
    const float* __restrict__ B, const unsigned* __restrict__ bminenc,
    u16* __restrict__ attno, int layer) {
  int w = threadIdx.x >> 6, l = threadIdx.x & 63;
  int g = l >> 4, c16 = l & 15;
  int hh = blockIdx.y;
  int q0 = blockIdx.x * 64 + w * 16;
  const float slopes[4] = {0.25f, 0.0625f, 0.015625f, 0.00390625f};
  float slope = slopes[hh];
  bool domask = (layer < 2) && (hh == 0);
  float bmin = fdec(*bminenc);
  bf16x8 aq[4];
  {
    const u16* qp = q + ((size_t)(hh * NT + q0 + c16)) * DH + g * 8;
    for (int kk = 0; kk < 4; ++kk) aq[kk] = *(const bf16x8*)(qp + kk * 32);
  }
  f32x4 O[8];
  for (int i = 0; i < 8; ++i) O[i] = (f32x4){0.f, 0.f, 0.f, 0.f};
  float mrow[4] = {-1e30f, -1e30f, -1e30f, -1e30f};
  float lrow[4] = {0.f, 0.f, 0.f, 0.f};
  __shared__ u16 P[4][16][72];
  for (int mt = 0; mt < NT; mt += 64) {
    f32x4 S[4];
    for (int c = 0; c < 4; ++c) S[c] = (f32x4){0.f, 0.f, 0.f, 0.f};
    for (int c = 0; c < 4; ++c) {
      const u16* kp = k + ((size_t)(hh * NT + mt + c * 16 + c16)) * DH + g * 8;
      for (int kk = 0; kk < 4; ++kk) {
        bf16x8 bk = *(const bf16x8*)(kp + kk * 32);
        S[c] = __builtin_amdgcn_mfma_f32_16x16x32_bf16(aq[kk], bk, S[c], 0, 0, 0);
      }
    }
    float p[4][4], fj[4];
    for (int j = 0; j < 4; ++j) {
      int n = q0 + 4 * g + j;
      const float* Br = B + (size_t)n * NT + mt;
      float sv[4];
      float mx = -1e30f;
      for (int c = 0; c < 4; ++c) {
        float bv = Br[c * 16 + c16];
        float sc = S[c][j] + slope * bv;
        if (domask && bv == bmin) sc = -INFINITY;
        sv[c] = sc;
        mx = fmaxf(mx, sc);
      }
      for (int d = 1; d < 16; d <<= 1) mx = fmaxf(mx, __shfl_xor(mx, d, 64));
      float mnew = fmaxf(mrow[j], mx);
      float f = __expf(mrow[j] - mnew);
      mrow[j] = mnew;
      float ps = 0.f;
      for (int c = 0; c < 4; ++c) {
        float pv = __expf(sv[c] - mnew);
        p[c][j] = pv;
        ps += pv;
      }
      for (int d = 1; d < 16; d <<= 1) ps += __shfl_xor(ps, d, 64);
      lrow[j] = lrow[j] * f + ps;
      fj[j] = f;
    }
    for (int df = 0; df < 8; ++df)
      for (int j = 0; j < 4; ++j) O[df][j] *= fj[j];
    for (int c = 0; c < 4; ++c)
      for (int j = 0; j < 4; ++j) P[w][4 * g + j][c * 16 + c16] = f2bf(p[c][j]);
    for (int kk2 = 0; kk2 < 2; ++kk2) {
      bf16x8 aP = *(const bf16x8*)&P[w][c16][kk2 * 32 + g * 8];
      for (int df = 0; df < 8; ++df) {
        const u16* vp = vt + ((size_t)(hh * DH + df * 16 + c16)) * NT + mt + kk2 * 32 + g * 8;
        bf16x8 bv = *(const bf16x8*)vp;
        O[df] = __builtin_amdgcn_mfma_f32_16x16x32_bf16(aP, bv, O[df], 0, 0, 0);
      }
    }
  }
  for (int df = 0; df < 8; ++df)
    for (int j = 0; j < 4; ++j) {
      int n = q0 + 4 * g + j;
      int d = df * 16 + c16;
      attno[(size_t)n * HID + hh * DH + d] = f2bf(O[df][j] / lrow[j]);
    }
}

// ---------------- final mean + LN + head ----------------
__global__ void colsum_kernel(const float* __restrict__ h, float* __restrict__ colsum) {
  int c = threadIdx.x;  // 512
  int r0 = blockIdx.x * 256;
  float s = 0.f;
  for (int r = 0; r < 256; ++r) s += h[(size_t)(r0 + r) * HID + c];
  atomicAdd(&colsum[c], s);
}

__global__ __launch_bounds__(512) void final_kernel(
    const float* __restrict__ colsum, const float* __restrict__ ns,
    const float* __restrict__ nb, const float* __restrict__ hw,
    const float* __restrict__ hb, float* __restrict__ out) {
  __shared__ float red[8];
  __shared__ float hm[512];
  int t = threadIdx.x;
  float v = colsum[t] * (1.f / (float)NT);
  float s = v;
  for (int d = 1; d < 64; d <<= 1) s += __shfl_xor(s, d, 64);
  if ((t & 63) == 0) red[t >> 6] = s;
  __syncthreads();
  float tot = 0.f;
  for (int i = 0; i < 8; ++i) tot += red[i];
  float mean = tot * (1.f / 512.f);
  __syncthreads();
  float dv = v - mean;
  float s2 = dv * dv;
  for (int d = 1; d < 64; d <<= 1) s2 += __shfl_xor(s2, d, 64);
  if ((t & 63) == 0) red[t >> 6] = s2;
  __syncthreads();
  float tot2 = 0.f;
  for (int i = 0; i < 8; ++i) tot2 += red[i];
  float rstd = rsqrtf(tot2 * (1.f / 512.f) + 1e-5f);
  hm[t] = dv * rstd * ns[t] + nb[t];
  __syncthreads();
  if (t < 64) {
    float a0 = 0.f, a1 = 0.f;
    for (int c = t; c < 512; c += 64) {
      a0 += hm[c] * hw[2 * c];
      a1 += hm[c] * hw[2 * c + 1];
    }
    for (int d = 1; d < 64; d <<= 1) {
      a0 += __shfl_xor(a0, d, 64);
      a1 += __shfl_xor(a1, d, 64);
    }
    if (t == 0) {
      out[0] = a0 + hb[0];
      out[1] = a1 + hb[1];
    }
  }
}

extern "C" void kernel_launch(void* const* d_in, const int* in_sizes, int n_in,
                              void* d_out, int out_size, void* d_ws, size_t ws_size,
                              hipStream_t stream) {
  const float* x = (const float*)d_in[0];
  const float* tbl = (const float*)d_in[1];
  const float* fc1_w = (const float*)d_in[2];
  const float* fc1_b = (const float*)d_in[3];
  const float* ln1_s = (const float*)d_in[4];
  const float* ln1_b = (const float*)d_in[5];
  const float* qkv_w = (const float*)d_in[6];
  const float* proj_w = (const float*)d_in[7];
  const float* proj_b = (const float*)d_in[8];
  const float* ln2_s = (const float*)d_in[9];
  const float* ln2_b = (const float*)d_in[10];
  const float* mlp1_w = (const float*)d_in[11];
  const float* mlp1_b = (const float*)d_in[12];
  const float* mlp2_w = (const float*)d_in[13];
  const float* mlp2_b = (const float*)d_in[14];
  const float* norm_s = (const float*)d_in[15];
  const float* norm_b = (const float*)d_in[16];
  const float* head_w = (const float*)d_in[17];
  const float* head_b = (const float*)d_in[18];
  float* out = (float*)d_out;

  char* ws = (char*)d_ws;
  size_t off = 0;
  auto alloc = [&](size_t bytes) -> char* {
    char* p = ws + off;
    off += (bytes + 255) & ~(size_t)255;
    return p;
  };
  u16* xin = (u16*)alloc((size_t)NT * INDIM * 2);
  u16* wfc1 = (u16*)alloc((size_t)INDIM * HID * 2);
  u16* wqkv = (u16*)alloc((size_t)3 * HID * 3 * HID * 2);
  u16* wproj = (u16*)alloc((size_t)3 * HID * HID * 2);
  u16* wmlp1 = (u16*)alloc((size_t)3 * HID * 4 * HID * 2);
  u16* wmlp2 = (u16*)alloc((size_t)3 * 4 * HID * HID * 2);
  float* h = (float*)alloc((size_t)NT * HID * 4);
  u16* xn = (u16*)alloc((size_t)NT * HID * 2);
  u16* qb_ = (u16*)alloc((size_t)NHEADS * NT * DH * 2);
  u16* kb_ = (u16*)alloc((size_t)NHEADS * NT * DH * 2);
  u16* vtb = (u16*)alloc((size_t)NHEADS * DH * NT * 2);
  u16* attno = (u16*)alloc((size_t)NT * HID * 2);
  u16* mid = (u16*)alloc((size_t)NT * 4 * HID * 2);
  float* Bm = (float*)alloc((size_t)NT * NT * 4);
  int* idx = (int*)alloc((size_t)NT * 4);
  float* colsum = (float*)alloc(512 * 4);
  float* cmin = (float*)alloc(2 * 4);
  unsigned* bminenc = (unsigned*)alloc(4);

  cast_x_kernel<<<1024, 256, 0, stream>>>(x, xin);
  cast_tr_kernel<<<512, 256, 0, stream>>>(fc1_w, wfc1, INDIM, HID);
  for (int l = 0; l < 3; ++l) {
    cast_tr_kernel<<<512, 256, 0, stream>>>(qkv_w + (size_t)l * HID * 3 * HID,
                                            wqkv + (size_t)l * 3 * HID * HID, HID, 3 * HID);
    cast_tr_kernel<<<256, 256, 0, stream>>>(proj_w + (size_t)l * HID * HID,
                                            wproj + (size_t)l * HID * HID, HID, HID);
    cast_tr_kernel<<<512, 256, 0, stream>>>(mlp1_w + (size_t)l * HID * 4 * HID,
                                            wmlp1 + (size_t)l * HID * 4 * HID, HID, 4 * HID);
    cast_tr_kernel<<<512, 256, 0, stream>>>(mlp2_w + (size_t)l * 4 * HID * HID,
                                            wmlp2 + (size_t)l * 4 * HID * HID, 4 * HID, HID);
  }
  init_kernel<<<1, 256, 0, stream>>>(colsum, bminenc);
  coordmin_kernel<<<1, 256, 0, stream>>>(x, cmin);
  idx_kernel<<<16, 256, 0, stream>>>(x, cmin, idx);
  bias_gather_kernel<<<NT, 256, 0, stream>>>(tbl, idx, Bm, bminenc);

  gemm_kernel<EPI_RELU><<<dim3(HID / 64, NT / 128), 256, 0, stream>>>(
      xin, wfc1, fc1_b, h, (u16*)nullptr, (u16*)nullptr, (u16*)nullptr, (u16*)nullptr, HID, INDIM);

  for (int l = 0; l < 3; ++l) {
    ln_kernel<<<NT / 4, 256, 0, stream>>>(h, ln1_s + l * HID, ln1_b + l * HID, xn);
    gemm_kernel<EPI_QKV><<<dim3(3 * HID / 64, NT / 128), 256, 0, stream>>>(
        xn, wqkv + (size_t)l * 3 * HID * HID, (const float*)nullptr, (float*)nullptr,
        (u16*)nullptr, qb_, kb_, vtb, 3 * HID, HID);
    attn_kernel<<<dim3(NT / 64, NHEADS), 256, 0, stream>>>(qb_, kb_, vtb, Bm, bminenc, attno, l);
    gemm_kernel<EPI_ADD><<<dim3(HID / 64, NT / 128), 256, 0, stream>>>(
        attno, wproj + (size_t)l * HID * HID, proj_b + l * HID, h, (u16*)nullptr, (u16*)nullptr,
        (u16*)nullptr, (u16*)nullptr, HID, HID);
    ln_kernel<<<NT / 4, 256, 0, stream>>>(h, ln2_s + l * HID, ln2_b + l * HID, xn);
    gemm_kernel<EPI_GELU><<<dim3(4 * HID / 64, NT / 128), 256, 0, stream>>>(
        xn, wmlp1 + (size_t)l * HID * 4 * HID, mlp1_b + l * 4 * HID, (float*)nullptr, mid,
        (u16*)nullptr, (u16*)nullptr, (u16*)nullptr, 4 * HID, HID);
    gemm_kernel<EPI_ADD><<<dim3(HID / 64, NT / 128), 256, 0, stream>>>(
        mid, wmlp2 + (size_t)l * 4 * HID * HID, mlp2_b + l * HID, h, (u16*)nullptr, (u16*)nullptr,
        (u16*)nullptr, (u16*)nullptr, HID, 4 * HID);
  }
  colsum_kernel<<<16, 512, 0, stream>>>(h, colsum);
  final_kernel<<<1, 512, 0, stream>>>(colsum, norm_s, norm_b, head_w, head_b, out);
}